// Round 7
// baseline (608.793 us; speedup 1.0000x reference)
//
#include <hip/hip_runtime.h>
#include <hip/hip_bf16.h>
#include <cstdint>

#define B_IMG   8
#define NCAND   36720
#define PD      85
#define NCLS    80
#define KC      512
#define MAXDET  300
#define NBUCK   2048
#define CANDCAP 1024      // gathered count is ~512 + one-bucket (<~40): 1024 is safe
#define PX1     9216      // 96*96 pixels, level 1 (bf16 G1)
#define PXA     3024      // 48*48 + 24*24 + 12*12, levels 2-4 (f32 Gacc)

typedef unsigned int u32;
typedef unsigned long long u64;

__device__ __forceinline__ float leaky(float x){ return x >= 0.f ? x : 0.01f*x; }

__device__ __forceinline__ u64 shfl_u64(u64 v, int lane){
  int lo = __shfl((int)(u32)(v & 0xFFFFFFFFull), lane, 64);
  int hi = __shfl((int)(u32)(v >> 32), lane, 64);
  return ((u64)(u32)hi << 32) | (u64)(u32)lo;
}
__device__ __forceinline__ u64 shfl_xor_u64(u64 v, int mask){
  int lo = __shfl_xor((int)(u32)(v & 0xFFFFFFFFull), mask, 64);
  int hi = __shfl_xor((int)(u32)(v >> 32), mask, 64);
  return ((u64)(u32)hi << 32) | (u64)(u32)lo;
}

// ---------------- K1: two-phase score: obj-filter -> class-scan survivors only ----
// Phase 1: lane = candidate, load obj (1 line/cand, unavoidable), ballot-
// compact survivors (~40%) into per-wave LDS. Phase 2: quads scan 80 classes
// for survivors only (skips ~60% of the 336B/row class reads + FMAs).
// Single store phase per lane: no same-address write ordering hazards.
__global__ __launch_bounds__(256) void k_score(const float* __restrict__ preds,
    u32* __restrict__ sbits, int* __restrict__ clsArr, u32* __restrict__ hist){
  __shared__ u32   sl_lane[4][64];
  __shared__ float sl_obj[4][64];
  __shared__ u32   sl_res[4][64];
  __shared__ u32   sl_cls[4][64];
  const int img  = blockIdx.y;
  const int wv   = threadIdx.x >> 6;
  const int lane = threadIdx.x & 63;
  const int base = (blockIdx.x*4 + wv)*64;
  const int ci   = base + lane;
  const bool inb = ci < NCAND;
  float obj = 0.f;
  if (inb) obj = preds[((long)img*NCAND + ci)*PD + 4];
  const bool pass = obj > 0.596f;
  u64 mask = __ballot(pass);
  int cnt  = __popcll(mask);
  int rank = __popcll(mask & ((1ull << lane) - 1ull));
  if (pass){ sl_lane[wv][rank] = (u32)lane; sl_obj[wv][rank] = obj; }
  const int q = lane & 3;
  for (int r0 = 0; r0 < cnt; r0 += 16){
    int idx = r0 + (lane >> 2);
    if (idx < cnt){
      u32 sl = sl_lane[wv][idx];
      float obj2 = sl_obj[wv][idx];
      const float* p2 = preds + ((long)img*NCAND + base + (int)sl)*PD + 5 + q;
      u64 best = 0ull;
      #pragma unroll
      for (int k = 0; k < 20; k++){
        float v = p2[4*k] * obj2;                       // exact ref: cls*obj
        u64 key = ((u64)__float_as_uint(v) << 32) | (u64)(~(u32)(q + 4*k));
        if (key > best) best = key;                     // first max wins
      }
      u64 o1 = shfl_xor_u64(best, 1); if (o1 > best) best = o1;
      u64 o2 = shfl_xor_u64(best, 2); if (o2 > best) best = o2;
      if (q == 0){
        u32 bits = (u32)(best >> 32);
        sl_res[wv][sl] = (__uint_as_float(bits) > 0.596f) ? bits : 0u;
        sl_cls[wv][sl] = ~(u32)(best & 0xFFFFFFFFull);
      }
    }
  }
  if (inb){
    u32 out = pass ? sl_res[wv][lane] : 0u;             // valid scores in (0.596,1)
    sbits[(long)img*NCAND + ci] = out;
    if (pass) clsArr[(long)img*NCAND + ci] = (int)sl_cls[wv][lane];
    if (out) atomicAdd(&hist[img*NBUCK + ((out - 0x3F000000u) >> 12)], 1u);
  }
}

// ---------------- K2: per-image bit-threshold covering top-512 ----------------
__global__ __launch_bounds__(64) void k_thresh(const u32* __restrict__ hist,
                                               u32* __restrict__ thr){
  const int img = blockIdx.x;
  const int lane = threadIdx.x;
  const u32* h = hist + img*NBUCK;
  u32 acc = 0; u32 result = 0x3F000000u; bool found = false;
  for (int g = NBUCK/64 - 1; g >= 0 && !found; g--){
    u32 v = h[g*64 + lane];
    u32 s = v;
    #pragma unroll
    for (int off = 1; off < 64; off <<= 1){
      u32 t = __shfl_down(s, off, 64);
      s += (lane + off < 64) ? t : 0u;
    }
    u64 mask = __ballot(acc + s >= KC);
    if (mask){
      int hl = 63 - __clzll(mask);
      result = 0x3F000000u + ((u32)(g*64 + hl) << 12);
      found = true;
    }
    acc += __shfl(s, 0, 64);
  }
  if (lane == 0) thr[img] = result;
}

// ---------------- K3: gather candidates >= threshold as sortable keys ----------------
__global__ __launch_bounds__(256) void k_gather(const u32* __restrict__ sbits,
    const u32* __restrict__ thr, u32* __restrict__ cnt, u64* __restrict__ cand){
  int img = blockIdx.y;
  int n = blockIdx.x*256 + threadIdx.x;
  if (n >= NCAND) return;
  u32 bits = sbits[(long)img*NCAND + n];
  if (bits && bits >= thr[img]){
    u32 pos = atomicAdd(&cnt[img], 1u);
    if (pos < CANDCAP)
      cand[(long)img*CANDCAP + pos] = ((u64)bits << 32) | (u64)(0xFFFFFFFFu - (u32)n);
  }
}

// ---------------- K4: fused NMS: rank -> decode -> IOU matrix -> greedy -> compact ----
__global__ __launch_bounds__(512) void k_nms(const float* __restrict__ preds,
    const int* __restrict__ clsArr, const u64* __restrict__ cand,
    const u32* __restrict__ cnt, float* __restrict__ selbox, u32* __restrict__ selcnt){
#pragma clang fp contract(off)
  __shared__ __align__(16) u64 keys[CANDCAP];      // 8 KB
  __shared__ float4 cbs[KC];                       // 8 KB  class-offset boxes
  __shared__ float4 obs[KC];                       // 8 KB  original boxes
  __shared__ u64 lrows[KC*8];                      // 32 KB suppression matrix
  __shared__ u64 kmask[8];
  __shared__ u64 keepw[8];
  const int img = blockIdx.x;
  const int tid = threadIdx.x;
  const int M = min((int)cnt[img], CANDCAP);
  keys[tid]       = (tid < M)       ? cand[(long)img*CANDCAP + tid]       : 0ull;
  keys[tid + 512] = (tid + 512 < M) ? cand[(long)img*CANDCAP + tid + 512] : 0ull;
  cbs[tid] = make_float4(-4e8f, -4e8f, -4e8f, -4e8f);   // zero-area -> iou 0
  obs[tid] = make_float4(0.f, 0.f, 0.f, 0.f);
  if (tid < 8) kmask[tid] = 0ull;
  __syncthreads();
  // ---- rank by count (desc): rank = #{keys strictly greater} ----
  u64 k0 = keys[tid], k1 = keys[tid + 512];
  int r0 = 0, r1 = 0;
  const ulonglong2* kv = (const ulonglong2*)keys;
  for (int j = 0; j < CANDCAP/2; j++){              // wave-uniform b128 broadcast
    ulonglong2 kk = kv[j];
    r0 += (kk.x > k0) + (kk.y > k0);
    r1 += (kk.x > k1) + (kk.y > k1);
  }
  #pragma unroll
  for (int t = 0; t < 2; t++){
    u64 key = t ? k1 : k0;
    int rank = t ? r1 : r0;
    if ((key >> 32) != 0ull && rank < KC){
      u32 idxn = 0xFFFFFFFFu - (u32)(key & 0xFFFFFFFFull);
      const float* p = preds + ((long)img*NCAND + idxn)*PD;
      float cx = p[0], cy = p[1], w = p[2], h = p[3];
      float hw = w*0.5f, hh = h*0.5f;               // exact
      float X1 = cx-hw, Y1 = cy-hh, X2 = cx+hw, Y2 = cy+hh;
      float off = (float)clsArr[(long)img*NCAND + idxn] * 4096.0f;  // exact
      obs[rank] = make_float4(X1, Y1, X2, Y2);
      cbs[rank] = make_float4(X1+off, Y1+off, X2+off, Y2+off);
      atomicOr(&kmask[rank >> 6], 1ull << (rank & 63));
    }
  }
  __syncthreads();
  {
    const int i = tid;
    float4 bi = cbs[i];
    float areai = (bi.z - bi.x)*(bi.w - bi.y);
    for (int w = 0; w < 8; w++){
      u64 bits = 0ull;
      int jbase = w*64;
      for (int b = 0; b < 64; b++){
        int j = jbase + b;
        if (j > i){
          float4 bj = cbs[j];
          float areaj = (bj.z - bj.x)*(bj.w - bj.y);
          float ltx = fmaxf(bi.x, bj.x), lty = fmaxf(bi.y, bj.y);
          float rbx = fminf(bi.z, bj.z), rby = fminf(bi.w, bj.w);
          float ww = fmaxf(rbx - ltx, 0.f);
          float hh = fmaxf(rby - lty, 0.f);
          float inter = ww*hh;
          float iou = inter / (areai + areaj - inter + 1e-7f);  // exact ref op order
          if (iou > 0.45f) bits |= (1ull << b);
        }
      }
      lrows[i*8 + w] = bits;
    }
  }
  __syncthreads();
  // ---- greedy: wave 0, lane-local blocked update ----
  if (tid < 64){
    const int lane = tid;
    const int w = lane & 7;
    u64 kw_own = kmask[w];
    for (int b = 0; b < 8; b++){
      u64 kwb = shfl_u64(kw_own, b);
      for (int g = 0; g < 8; g++){
        u64 rdec[8], rown[8];
        #pragma unroll
        for (int k = 0; k < 8; k++){
          int i = b*64 + g*8 + k;
          rdec[k] = lrows[i*8 + b];
          rown[k] = lrows[i*8 + w];
        }
        #pragma unroll
        for (int k = 0; k < 8; k++){
          int il = g*8 + k;
          if ((kwb >> il) & 1ull){
            kwb    &= ~rdec[k];
            kw_own &= ~rown[k];
          }
        }
      }
    }
    if (lane < 8) keepw[lane] = kw_own;
  }
  __syncthreads();
  {
    u64 kk[8];
    #pragma unroll
    for (int w = 0; w < 8; w++) kk[w] = keepw[w];
    const int s = tid;
    const int wi = s >> 6, bi = s & 63;
    bool kept = (kk[wi] >> bi) & 1ull;
    if (kept){
      int rank = 0;
      for (int w = 0; w < wi; w++) rank += __popcll(kk[w]);
      rank += __popcll(bi ? (kk[wi] & ((1ull << bi) - 1ull)) : 0ull);
      if (rank < MAXDET){
        float4 ob = obs[s];
        float* sb = selbox + ((long)img*MAXDET + rank)*4;
        sb[0]=ob.x; sb[1]=ob.y; sb[2]=ob.z; sb[3]=ob.w;
      }
    }
    if (tid == 0){
      int tot = 0;
      #pragma unroll
      for (int w = 0; w < 8; w++) tot += __popcll(kk[w]);
      selcnt[img] = (u32)min(tot, MAXDET);
    }
  }
}

// ---------------- K5: projection, lane = pixel, W via scalar loads ----------------
// Wave unit = (64-px tile) x (128-ch chunk). Feat loads: per-lane coalesced
// 256B, each element read once chip-wide. W row address depends only on block
// constants + c -> provably uniform -> s_load_dwordx16 (scalar pipe), inner
// loop = 64 v_fmac with 64-deep accumulator ILP. Store via per-wave LDS
// 64x17 transpose tile (intra-wave, no barriers). 276 units x 8 img.
__global__ __launch_bounds__(256) void k_proj(const float* __restrict__ f1,
    const float* __restrict__ f2, const float* __restrict__ f3,
    const float* __restrict__ f4, const float* __restrict__ W1,
    __hip_bfloat16* __restrict__ G1, float* __restrict__ Gacc){
  __shared__ float tbuf[4][64*17];
  const int img  = blockIdx.y;
  const int wv   = threadIdx.x >> 6;
  const int lane = threadIdx.x & 63;
  const int u    = blockIdx.x*4 + wv;          // 69*4 = 276 units
  const float* feat; int C, HW, tile, chunk, Woff, accoff; bool lvl1 = false;
  if (u < 144){      feat=f1; C=128;  HW=9216; tile=u;      chunk=0;    Woff=0;   accoff=0;    lvl1=true; }
  else if (u < 216){ int s=u-144; feat=f2; C=256;  HW=2304; tile=s>>1;  chunk=s&1; Woff=128; accoff=0; }
  else if (u < 252){ int s=u-216; feat=f3; C=512;  HW=576;  tile=s>>2;  chunk=s&3; Woff=384; accoff=2304; }
  else {             int s=u-252; feat=f4; C=1024; HW=144;  tile=s>>3;  chunk=s&7; Woff=896; accoff=2880; }
  const int p = tile*64 + lane;
  const int pc = (p < HW) ? p : (HW-1);
  const float* fp = feat + ((long)img*C + chunk*128)*HW + pc;
  const float* Wp = W1 + (long)(Woff + chunk*128)*64;     // block-uniform
  float acc[64];
  #pragma unroll
  for (int j = 0; j < 64; j++) acc[j] = 0.f;
  #pragma unroll 2
  for (int c = 0; c < 128; c++){
    float v = fp[(long)c*HW];                             // coalesced 256B/wave
    const float* wr = Wp + c*64;                          // uniform -> SGPR
    #pragma unroll
    for (int j = 0; j < 64; j++) acc[j] = fmaf(wr[j], v, acc[j]);
  }
  // transpose via LDS in 4 j-rounds of 16 (intra-wave only)
  for (int j0 = 0; j0 < 64; j0 += 16){
    #pragma unroll
    for (int jj = 0; jj < 16; jj++) tbuf[wv][lane*17 + jj] = acc[j0 + jj];
    const int jl = lane & 15;
    const int pg = lane >> 4;
    #pragma unroll
    for (int r = 0; r < 16; r++){
      int px = r*4 + pg;
      float v = tbuf[wv][px*17 + jl];
      int gp = tile*64 + px;
      if (gp < HW){
        if (lvl1)
          G1[((long)img*PX1 + gp)*64 + j0 + jl] = __float2bfloat16(v);
        else
          atomicAdd(&Gacc[((long)img*PXA + accoff + gp)*64 + j0 + jl], v);
      }
    }
  }
}

// ---------------- K6: fused ROI-gather + bias + leaky + layer2 + assembly ----------------
template <typename T>
__device__ __forceinline__ float gread(const T* g, long off, int lane);
template <> __device__ __forceinline__ float gread<__hip_bfloat16>(
    const __hip_bfloat16* g, long off, int lane){ return __bfloat162float(g[off*64+lane]); }
template <> __device__ __forceinline__ float gread<float>(
    const float* g, long off, int lane){ return g[off*64+lane]; }

template <typename T>
__device__ __forceinline__ void roi_level(const T* __restrict__ g,
    int Hl, int Wl, float scale, float x1, float y1, float x2, float y2,
    int lane, float& h){
  float bx1=x1*scale, by1=y1*scale, bx2=x2*scale, by2=y2*scale;
  float rw=fmaxf(bx2-bx1,1.f), rh=fmaxf(by2-by1,1.f);
  float ys[2]={by1+rh*0.25f, by1+rh*0.75f};
  float xs[2]={bx1+rw*0.25f, bx1+rw*0.75f};
  #pragma unroll
  for (int pt = 0; pt < 4; pt++){
    float y=ys[pt>>1], x=xs[pt&1];
    if ((y>-1.f)&&(y<(float)Hl)&&(x>-1.f)&&(x<(float)Wl)){   // wave-uniform branch
      float yc=fmaxf(y,0.f), xc=fmaxf(x,0.f);
      int y0=(int)fminf(floorf(yc),(float)(Hl-1));
      int x0=(int)fminf(floorf(xc),(float)(Wl-1));
      int y1i=min(y0+1,Hl-1), x1i=min(x0+1,Wl-1);
      float ly=yc-(float)y0, lx=xc-(float)x0;
      float hy=1.f-ly, hx=1.f-lx;
      h += (hy*hx*0.25f)*gread(g,(long)(y0*Wl+x0),lane);
      h += (hy*lx*0.25f)*gread(g,(long)(y0*Wl+x1i),lane);
      h += (ly*hx*0.25f)*gread(g,(long)(y1i*Wl+x0),lane);
      h += (ly*lx*0.25f)*gread(g,(long)(y1i*Wl+x1i),lane);
    }
  }
}

__global__ __launch_bounds__(256) void k_roi_mlp(const __hip_bfloat16* __restrict__ G1,
    const float* __restrict__ Gacc,
    const float* __restrict__ selbox, const u32* __restrict__ selcnt,
    const float* __restrict__ b1, const float* __restrict__ W2,
    const float* __restrict__ b2, float* __restrict__ out){
  const int img  = blockIdx.y;
  const int wave = threadIdx.x >> 6;
  const int lane = threadIdx.x & 63;
  const int slot = blockIdx.x*4 + wave;
  if (slot >= MAXDET) return;
  float* o = out + ((long)img*MAXDET + slot)*68;
  if (slot >= (int)selcnt[img]){
    o[4+lane] = 0.f;
    if (lane < 4) o[lane] = 0.f;
    return;
  }
  const float* sb = selbox + ((long)img*MAXDET + slot)*4;
  float x1 = sb[0], y1 = sb[1], x2 = sb[2], y2 = sb[3];
  const __hip_bfloat16* G1i = G1 + (long)img*PX1*64;
  const float* Gai = Gacc + (long)img*PXA*64;
  float h = 0.f;
  roi_level(G1i,            96, 96, 0.125f,    x1,y1,x2,y2, lane, h);
  roi_level(Gai,            48, 48, 0.0625f,   x1,y1,x2,y2, lane, h);
  roi_level(Gai + 2304*64,  24, 24, 0.03125f,  x1,y1,x2,y2, lane, h);
  roi_level(Gai + 2880*64,  12, 12, 0.015625f, x1,y1,x2,y2, lane, h);
  float h1 = leaky(h + b1[lane]);
  float c = 0.f;
  #pragma unroll 8
  for (int k = 0; k < 64; k++){
    float hk = __shfl(h1, k, 64);
    c += hk * W2[k*64 + lane];
  }
  o[4+lane] = leaky(c + b2[lane]);
  if (lane < 4) o[lane] = sb[lane] / 768.0f;
}

// ---------------- workspace layout (bytes) ----------------
// 0         hist    u32[8][2048]       65536
// 65536     cnt     u32[8]             256 (padded)
// 65792     thr     u32[8]             256
// 66048     selbox  f32[8][300][4]     38400
// 104448    selcnt  u32[8]             256
// 104704    sbits   u32[8][36720]      1175040
// 1279744   cls     i32[8][36720]      1175040
// 2454784   cand    u64[8][1024]       65536
// 2520320   G1      bf16[8][9216][64]  9437184
// 11957504  Gacc    f32[8][3024][64]   6193152   -> total ~18.2 MB

extern "C" void kernel_launch(void* const* d_in, const int* in_sizes, int n_in,
                              void* d_out, int out_size, void* d_ws, size_t ws_size,
                              hipStream_t stream){
  const float* preds = (const float*)d_in[0];
  const float* f1 = (const float*)d_in[1];
  const float* f2 = (const float*)d_in[2];
  const float* f3 = (const float*)d_in[3];
  const float* f4 = (const float*)d_in[4];
  const float* W1 = (const float*)d_in[5];
  const float* b1 = (const float*)d_in[6];
  const float* W2 = (const float*)d_in[7];
  const float* b2 = (const float*)d_in[8];
  float* out = (float*)d_out;
  char* ws = (char*)d_ws;
  u32* hist   = (u32*)(ws + 0);
  u32* cnt    = (u32*)(ws + 65536);
  u32* thr    = (u32*)(ws + 65792);
  float* selb = (float*)(ws + 66048);
  u32* selc   = (u32*)(ws + 104448);
  u32* sbits  = (u32*)(ws + 104704);
  int* clsA   = (int*)(ws + 1279744);
  u64* cand   = (u64*)(ws + 2454784);
  __hip_bfloat16* G1 = (__hip_bfloat16*)(ws + 2520320);
  float* Gacc = (float*)(ws + 11957504);

  hipMemsetAsync(ws, 0, 65792, stream);                       // hist + cnt
  hipMemsetAsync(Gacc, 0, (size_t)B_IMG*PXA*64*4, stream);    // K-split accumulator

  dim3 gs((NCAND + 255)/256, B_IMG);
  k_score<<<gs, 256, 0, stream>>>(preds, sbits, clsA, hist);
  k_thresh<<<B_IMG, 64, 0, stream>>>(hist, thr);
  dim3 g3((NCAND+255)/256, B_IMG);
  k_gather<<<g3, 256, 0, stream>>>(sbits, thr, cnt, cand);
  k_nms<<<B_IMG, 512, 0, stream>>>(preds, clsA, cand, cnt, selb, selc);
  k_proj<<<dim3(69, B_IMG), 256, 0, stream>>>(f1, f2, f3, f4, W1, G1, Gacc);
  k_roi_mlp<<<dim3((MAXDET+3)/4, B_IMG), 256, 0, stream>>>(G1, Gacc, selb, selc, b1, W2, b2, out);
}

// Round 8
// 444.792 us; speedup vs baseline: 1.3687x; 1.3687x over previous
//
#include <hip/hip_runtime.h>
#include <hip/hip_bf16.h>
#include <cstdint>

#define B_IMG   8
#define NCAND   36720
#define PD      85
#define NCLS    80
#define KC      512
#define MAXDET  300
#define NBUCK   2048
#define CANDCAP 1024      // gathered count is ~512 + one-bucket (<~40): 1024 is safe
#define PPI     12240     // projected pixels/img: 96*96 + 48*48 + 24*24 + 12*12
#define OFF_L2  9216
#define OFF_L3  11520
#define OFF_L4  12096

typedef unsigned int u32;
typedef unsigned long long u64;
typedef unsigned short ushort_t;

__device__ __forceinline__ float leaky(float x){ return x >= 0.f ? x : 0.01f*x; }

__device__ __forceinline__ u64 shfl_u64(u64 v, int lane){
  int lo = __shfl((int)(u32)(v & 0xFFFFFFFFull), lane, 64);
  int hi = __shfl((int)(u32)(v >> 32), lane, 64);
  return ((u64)(u32)hi << 32) | (u64)(u32)lo;
}
__device__ __forceinline__ u64 shfl_xor_u64(u64 v, int mask){
  int lo = __shfl_xor((int)(u32)(v & 0xFFFFFFFFull), mask, 64);
  int hi = __shfl_xor((int)(u32)(v >> 32), mask, 64);
  return ((u64)(u32)hi << 32) | (u64)(u32)lo;
}

// ---------------- K1: two-phase score: obj-filter -> class-scan survivors only ----
__global__ __launch_bounds__(256) void k_score(const float* __restrict__ preds,
    u32* __restrict__ sbits, int* __restrict__ clsArr, u32* __restrict__ hist){
  __shared__ u32   sl_lane[4][64];
  __shared__ float sl_obj[4][64];
  __shared__ u32   sl_res[4][64];
  __shared__ u32   sl_cls[4][64];
  const int img  = blockIdx.y;
  const int wv   = threadIdx.x >> 6;
  const int lane = threadIdx.x & 63;
  const int base = (blockIdx.x*4 + wv)*64;
  const int ci   = base + lane;
  const bool inb = ci < NCAND;
  float obj = 0.f;
  if (inb) obj = preds[((long)img*NCAND + ci)*PD + 4];
  const bool pass = obj > 0.596f;
  u64 mask = __ballot(pass);
  int cnt  = __popcll(mask);
  int rank = __popcll(mask & ((1ull << lane) - 1ull));
  if (pass){ sl_lane[wv][rank] = (u32)lane; sl_obj[wv][rank] = obj; }
  const int q = lane & 3;
  for (int r0 = 0; r0 < cnt; r0 += 16){
    int idx = r0 + (lane >> 2);
    if (idx < cnt){
      u32 sl = sl_lane[wv][idx];
      float obj2 = sl_obj[wv][idx];
      const float* p2 = preds + ((long)img*NCAND + base + (int)sl)*PD + 5 + q;
      u64 best = 0ull;
      #pragma unroll
      for (int k = 0; k < 20; k++){
        float v = p2[4*k] * obj2;                       // exact ref: cls*obj
        u64 key = ((u64)__float_as_uint(v) << 32) | (u64)(~(u32)(q + 4*k));
        if (key > best) best = key;                     // first max wins
      }
      u64 o1 = shfl_xor_u64(best, 1); if (o1 > best) best = o1;
      u64 o2 = shfl_xor_u64(best, 2); if (o2 > best) best = o2;
      if (q == 0){
        u32 bits = (u32)(best >> 32);
        sl_res[wv][sl] = (__uint_as_float(bits) > 0.596f) ? bits : 0u;
        sl_cls[wv][sl] = ~(u32)(best & 0xFFFFFFFFull);
      }
    }
  }
  if (inb){
    u32 out = pass ? sl_res[wv][lane] : 0u;             // valid scores in (0.596,1)
    sbits[(long)img*NCAND + ci] = out;
    if (pass) clsArr[(long)img*NCAND + ci] = (int)sl_cls[wv][lane];
    if (out) atomicAdd(&hist[img*NBUCK + ((out - 0x3F000000u) >> 12)], 1u);
  }
}

// ---------------- K2: per-image bit-threshold covering top-512 ----------------
__global__ __launch_bounds__(64) void k_thresh(const u32* __restrict__ hist,
                                               u32* __restrict__ thr){
  const int img = blockIdx.x;
  const int lane = threadIdx.x;
  const u32* h = hist + img*NBUCK;
  u32 acc = 0; u32 result = 0x3F000000u; bool found = false;
  for (int g = NBUCK/64 - 1; g >= 0 && !found; g--){
    u32 v = h[g*64 + lane];
    u32 s = v;
    #pragma unroll
    for (int off = 1; off < 64; off <<= 1){
      u32 t = __shfl_down(s, off, 64);
      s += (lane + off < 64) ? t : 0u;
    }
    u64 mask = __ballot(acc + s >= KC);
    if (mask){
      int hl = 63 - __clzll(mask);
      result = 0x3F000000u + ((u32)(g*64 + hl) << 12);
      found = true;
    }
    acc += __shfl(s, 0, 64);
  }
  if (lane == 0) thr[img] = result;
}

// ---------------- K3: gather candidates >= threshold as sortable keys ----------------
__global__ __launch_bounds__(256) void k_gather(const u32* __restrict__ sbits,
    const u32* __restrict__ thr, u32* __restrict__ cnt, u64* __restrict__ cand){
  int img = blockIdx.y;
  int n = blockIdx.x*256 + threadIdx.x;
  if (n >= NCAND) return;
  u32 bits = sbits[(long)img*NCAND + n];
  if (bits && bits >= thr[img]){
    u32 pos = atomicAdd(&cnt[img], 1u);
    if (pos < CANDCAP)
      cand[(long)img*CANDCAP + pos] = ((u64)bits << 32) | (u64)(0xFFFFFFFFu - (u32)n);
  }
}

// ---------------- K4: fused NMS: rank -> decode -> IOU matrix -> greedy -> compact ----
__global__ __launch_bounds__(512) void k_nms(const float* __restrict__ preds,
    const int* __restrict__ clsArr, const u64* __restrict__ cand,
    const u32* __restrict__ cnt, float* __restrict__ selbox, u32* __restrict__ selcnt){
#pragma clang fp contract(off)
  __shared__ __align__(16) u64 keys[CANDCAP];      // 8 KB
  __shared__ float4 cbs[KC];                       // 8 KB  class-offset boxes
  __shared__ float4 obs[KC];                       // 8 KB  original boxes
  __shared__ u64 lrows[KC*8];                      // 32 KB suppression matrix
  __shared__ u64 kmask[8];
  __shared__ u64 keepw[8];
  const int img = blockIdx.x;
  const int tid = threadIdx.x;
  const int M = min((int)cnt[img], CANDCAP);
  keys[tid]       = (tid < M)       ? cand[(long)img*CANDCAP + tid]       : 0ull;
  keys[tid + 512] = (tid + 512 < M) ? cand[(long)img*CANDCAP + tid + 512] : 0ull;
  cbs[tid] = make_float4(-4e8f, -4e8f, -4e8f, -4e8f);   // zero-area -> iou 0
  obs[tid] = make_float4(0.f, 0.f, 0.f, 0.f);
  if (tid < 8) kmask[tid] = 0ull;
  __syncthreads();
  // ---- rank by count (desc): rank = #{keys strictly greater} ----
  u64 k0 = keys[tid], k1 = keys[tid + 512];
  int r0 = 0, r1 = 0;
  const ulonglong2* kv = (const ulonglong2*)keys;
  for (int j = 0; j < CANDCAP/2; j++){              // wave-uniform b128 broadcast
    ulonglong2 kk = kv[j];
    r0 += (kk.x > k0) + (kk.y > k0);
    r1 += (kk.x > k1) + (kk.y > k1);
  }
  #pragma unroll
  for (int t = 0; t < 2; t++){
    u64 key = t ? k1 : k0;
    int rank = t ? r1 : r0;
    if ((key >> 32) != 0ull && rank < KC){
      u32 idxn = 0xFFFFFFFFu - (u32)(key & 0xFFFFFFFFull);
      const float* p = preds + ((long)img*NCAND + idxn)*PD;
      float cx = p[0], cy = p[1], w = p[2], h = p[3];
      float hw = w*0.5f, hh = h*0.5f;               // exact
      float X1 = cx-hw, Y1 = cy-hh, X2 = cx+hw, Y2 = cy+hh;
      float off = (float)clsArr[(long)img*NCAND + idxn] * 4096.0f;  // exact
      obs[rank] = make_float4(X1, Y1, X2, Y2);
      cbs[rank] = make_float4(X1+off, Y1+off, X2+off, Y2+off);
      atomicOr(&kmask[rank >> 6], 1ull << (rank & 63));
    }
  }
  __syncthreads();
  {
    const int i = tid;
    float4 bi = cbs[i];
    float areai = (bi.z - bi.x)*(bi.w - bi.y);
    for (int w = 0; w < 8; w++){
      u64 bits = 0ull;
      int jbase = w*64;
      for (int b = 0; b < 64; b++){
        int j = jbase + b;
        if (j > i){
          float4 bj = cbs[j];
          float areaj = (bj.z - bj.x)*(bj.w - bj.y);
          float ltx = fmaxf(bi.x, bj.x), lty = fmaxf(bi.y, bj.y);
          float rbx = fminf(bi.z, bj.z), rby = fminf(bi.w, bj.w);
          float ww = fmaxf(rbx - ltx, 0.f);
          float hh = fmaxf(rby - lty, 0.f);
          float inter = ww*hh;
          float iou = inter / (areai + areaj - inter + 1e-7f);  // exact ref op order
          if (iou > 0.45f) bits |= (1ull << b);
        }
      }
      lrows[i*8 + w] = bits;
    }
  }
  __syncthreads();
  // ---- greedy: wave 0, lane-local blocked update ----
  if (tid < 64){
    const int lane = tid;
    const int w = lane & 7;
    u64 kw_own = kmask[w];
    for (int b = 0; b < 8; b++){
      u64 kwb = shfl_u64(kw_own, b);
      for (int g = 0; g < 8; g++){
        u64 rdec[8], rown[8];
        #pragma unroll
        for (int k = 0; k < 8; k++){
          int i = b*64 + g*8 + k;
          rdec[k] = lrows[i*8 + b];
          rown[k] = lrows[i*8 + w];
        }
        #pragma unroll
        for (int k = 0; k < 8; k++){
          int il = g*8 + k;
          if ((kwb >> il) & 1ull){
            kwb    &= ~rdec[k];
            kw_own &= ~rown[k];
          }
        }
      }
    }
    if (lane < 8) keepw[lane] = kw_own;
  }
  __syncthreads();
  {
    u64 kk[8];
    #pragma unroll
    for (int w = 0; w < 8; w++) kk[w] = keepw[w];
    const int s = tid;
    const int wi = s >> 6, bi = s & 63;
    bool kept = (kk[wi] >> bi) & 1ull;
    if (kept){
      int rank = 0;
      for (int w = 0; w < wi; w++) rank += __popcll(kk[w]);
      rank += __popcll(bi ? (kk[wi] & ((1ull << bi) - 1ull)) : 0ull);
      if (rank < MAXDET){
        float4 ob = obs[s];
        float* sb = selbox + ((long)img*MAXDET + rank)*4;
        sb[0]=ob.x; sb[1]=ob.y; sb[2]=ob.z; sb[3]=ob.w;
      }
    }
    if (tid == 0){
      int tot = 0;
      #pragma unroll
      for (int w = 0; w < 8; w++) tot += __popcll(kk[w]);
      selcnt[img] = (u32)min(tot, MAXDET);
    }
  }
}

// ---------------- K5: projection as canonical LDS-tiled GEMM ----------------
// Block = 64px x 64j output tile over FULL K (C_lvl), K-chunks of 32 staged in
// LDS (Fs 8KB + Ws 8KB). Thread = 4px x 4j micro-tile -> acc[16] (no spill;
// R7's acc[64] spilled: VGPR=56 + 25GB scratch). Inner iter: 2 ds_read_b128 +
// 16 v_fma. Fs reads 2-way bank-aliased (free, m136); Ws reads broadcast.
// Full-K per block => no atomics, single bf16 G. Heavy levels (L4: 32 chunks)
// get lowest blockIdx so they start first (R3 tail lesson). 192x8 blocks.
__global__ __launch_bounds__(256) void k_proj(const float* __restrict__ f1,
    const float* __restrict__ f2, const float* __restrict__ f3,
    const float* __restrict__ f4, const float* __restrict__ W1,
    __hip_bfloat16* __restrict__ G){
  __shared__ __align__(16) float Fs[32*64];
  __shared__ __align__(16) float Ws[32*64];
  const int img = blockIdx.y;
  const int u   = blockIdx.x;
  const float* feat; int C, HW, Woff, lvl_off, tile;
  if (u < 3)       { feat=f4; C=1024; HW=144;  Woff=896; lvl_off=OFF_L4; tile=u; }
  else if (u < 12) { feat=f3; C=512;  HW=576;  Woff=384; lvl_off=OFF_L3; tile=u-3; }
  else if (u < 48) { feat=f2; C=256;  HW=2304; Woff=128; lvl_off=OFF_L2; tile=u-12; }
  else             { feat=f1; C=128;  HW=9216; Woff=0;   lvl_off=0;      tile=u-48; }
  const int px0  = tile*64;
  const int hw4  = HW >> 2;
  const int px04 = px0 >> 2;
  const int tid  = threadIdx.x;
  const int tx   = tid & 15;        // px group
  const int ty   = tid >> 4;        // j group
  const float4* feat4 = (const float4*)feat;
  const float4* W14   = (const float4*)W1;
  float4* Fs4 = (float4*)Fs;
  float4* Ws4 = (float4*)Ws;
  float a00=0,a01=0,a02=0,a03=0, a10=0,a11=0,a12=0,a13=0;
  float a20=0,a21=0,a22=0,a23=0, a30=0,a31=0,a32=0,a33=0;
  const long fbase = (long)img*C*hw4;
  for (int c0 = 0; c0 < C; c0 += 32){
    __syncthreads();
    #pragma unroll
    for (int s = tid; s < 512; s += 256){
      int c = s >> 4, q = s & 15;
      int pq = px04 + q;
      if (pq >= hw4) pq = hw4 - 1;               // ragged L4 tile: clamp (stores guarded)
      Fs4[s] = feat4[fbase + (long)(c0 + c)*hw4 + pq];
      Ws4[s] = W14[(long)(Woff + c0 + c)*16 + q];
    }
    __syncthreads();
    #pragma unroll 8
    for (int c = 0; c < 32; c++){
      float4 fv = Fs4[c*16 + tx];
      float4 wv = Ws4[c*16 + ty];
      a00 = fmaf(fv.x, wv.x, a00); a01 = fmaf(fv.x, wv.y, a01);
      a02 = fmaf(fv.x, wv.z, a02); a03 = fmaf(fv.x, wv.w, a03);
      a10 = fmaf(fv.y, wv.x, a10); a11 = fmaf(fv.y, wv.y, a11);
      a12 = fmaf(fv.y, wv.z, a12); a13 = fmaf(fv.y, wv.w, a13);
      a20 = fmaf(fv.z, wv.x, a20); a21 = fmaf(fv.z, wv.y, a21);
      a22 = fmaf(fv.z, wv.z, a22); a23 = fmaf(fv.z, wv.w, a23);
      a30 = fmaf(fv.w, wv.x, a30); a31 = fmaf(fv.w, wv.y, a31);
      a32 = fmaf(fv.w, wv.z, a32); a33 = fmaf(fv.w, wv.w, a33);
    }
  }
  float rows[4][4] = {{a00,a01,a02,a03},{a10,a11,a12,a13},
                      {a20,a21,a22,a23},{a30,a31,a32,a33}};
  #pragma unroll
  for (int p = 0; p < 4; p++){
    int gp = px0 + tx*4 + p;
    if (gp < px0 + 64 && gp < HW){   // guard only matters for ragged L4 tile
      __hip_bfloat16 h0 = __float2bfloat16(rows[p][0]);
      __hip_bfloat16 h1 = __float2bfloat16(rows[p][1]);
      __hip_bfloat16 h2 = __float2bfloat16(rows[p][2]);
      __hip_bfloat16 h3 = __float2bfloat16(rows[p][3]);
      ushort4 v;
      v.x = *(ushort_t*)&h0; v.y = *(ushort_t*)&h1;
      v.z = *(ushort_t*)&h2; v.w = *(ushort_t*)&h3;
      *(ushort4*)(G + ((long)img*PPI + lvl_off + gp)*64 + ty*4) = v;
    }
  }
}

// ---------------- K6: fused ROI-gather + bias + leaky + layer2 + assembly ----------------
__device__ __forceinline__ void roi_level(const __hip_bfloat16* __restrict__ g,
    int Hl, int Wl, float scale, float x1, float y1, float x2, float y2,
    int lane, float& h){
  float bx1=x1*scale, by1=y1*scale, bx2=x2*scale, by2=y2*scale;
  float rw=fmaxf(bx2-bx1,1.f), rh=fmaxf(by2-by1,1.f);
  float ys[2]={by1+rh*0.25f, by1+rh*0.75f};
  float xs[2]={bx1+rw*0.25f, bx1+rw*0.75f};
  #pragma unroll
  for (int pt = 0; pt < 4; pt++){
    float y=ys[pt>>1], x=xs[pt&1];
    if ((y>-1.f)&&(y<(float)Hl)&&(x>-1.f)&&(x<(float)Wl)){   // wave-uniform branch
      float yc=fmaxf(y,0.f), xc=fmaxf(x,0.f);
      int y0=(int)fminf(floorf(yc),(float)(Hl-1));
      int x0=(int)fminf(floorf(xc),(float)(Wl-1));
      int y1i=min(y0+1,Hl-1), x1i=min(x0+1,Wl-1);
      float ly=yc-(float)y0, lx=xc-(float)x0;
      float hy=1.f-ly, hx=1.f-lx;
      h += (hy*hx*0.25f)*__bfloat162float(g[(long)(y0*Wl+x0)*64+lane]);
      h += (hy*lx*0.25f)*__bfloat162float(g[(long)(y0*Wl+x1i)*64+lane]);
      h += (ly*hx*0.25f)*__bfloat162float(g[(long)(y1i*Wl+x0)*64+lane]);
      h += (ly*lx*0.25f)*__bfloat162float(g[(long)(y1i*Wl+x1i)*64+lane]);
    }
  }
}

__global__ __launch_bounds__(256) void k_roi_mlp(const __hip_bfloat16* __restrict__ G,
    const float* __restrict__ selbox, const u32* __restrict__ selcnt,
    const float* __restrict__ b1, const float* __restrict__ W2,
    const float* __restrict__ b2, float* __restrict__ out){
  const int img  = blockIdx.y;
  const int wave = threadIdx.x >> 6;
  const int lane = threadIdx.x & 63;
  const int slot = blockIdx.x*4 + wave;
  if (slot >= MAXDET) return;
  float* o = out + ((long)img*MAXDET + slot)*68;
  if (slot >= (int)selcnt[img]){
    o[4+lane] = 0.f;
    if (lane < 4) o[lane] = 0.f;
    return;
  }
  const float* sb = selbox + ((long)img*MAXDET + slot)*4;
  float x1 = sb[0], y1 = sb[1], x2 = sb[2], y2 = sb[3];
  const __hip_bfloat16* Gi = G + (long)img*PPI*64;
  float h = 0.f;
  roi_level(Gi,               96, 96, 0.125f,    x1,y1,x2,y2, lane, h);
  roi_level(Gi + OFF_L2*64,   48, 48, 0.0625f,   x1,y1,x2,y2, lane, h);
  roi_level(Gi + OFF_L3*64,   24, 24, 0.03125f,  x1,y1,x2,y2, lane, h);
  roi_level(Gi + OFF_L4*64,   12, 12, 0.015625f, x1,y1,x2,y2, lane, h);
  float h1 = leaky(h + b1[lane]);
  float c = 0.f;
  #pragma unroll 8
  for (int k = 0; k < 64; k++){
    float hk = __shfl(h1, k, 64);
    c += hk * W2[k*64 + lane];
  }
  o[4+lane] = leaky(c + b2[lane]);
  if (lane < 4) o[lane] = sb[lane] / 768.0f;
}

// ---------------- workspace layout (bytes) ----------------
// 0        hist    u32[8][2048]        65536
// 65536    cnt     u32[8]              256 (padded)
// 65792    thr     u32[8]              256
// 66048    selbox  f32[8][300][4]      38400
// 104448   selcnt  u32[8]              256
// 104704   sbits   u32[8][36720]       1175040
// 1279744  cls     i32[8][36720]       1175040
// 2454784  cand    u64[8][1024]        65536
// 2520320  G       bf16[8][12240][64]  12533760   -> total ~15.1 MB

extern "C" void kernel_launch(void* const* d_in, const int* in_sizes, int n_in,
                              void* d_out, int out_size, void* d_ws, size_t ws_size,
                              hipStream_t stream){
  const float* preds = (const float*)d_in[0];
  const float* f1 = (const float*)d_in[1];
  const float* f2 = (const float*)d_in[2];
  const float* f3 = (const float*)d_in[3];
  const float* f4 = (const float*)d_in[4];
  const float* W1 = (const float*)d_in[5];
  const float* b1 = (const float*)d_in[6];
  const float* W2 = (const float*)d_in[7];
  const float* b2 = (const float*)d_in[8];
  float* out = (float*)d_out;
  char* ws = (char*)d_ws;
  u32* hist   = (u32*)(ws + 0);
  u32* cnt    = (u32*)(ws + 65536);
  u32* thr    = (u32*)(ws + 65792);
  float* selb = (float*)(ws + 66048);
  u32* selc   = (u32*)(ws + 104448);
  u32* sbits  = (u32*)(ws + 104704);
  int* clsA   = (int*)(ws + 1279744);
  u64* cand   = (u64*)(ws + 2454784);
  __hip_bfloat16* G = (__hip_bfloat16*)(ws + 2520320);

  hipMemsetAsync(ws, 0, 65792, stream);   // hist + cnt

  dim3 gs((NCAND + 255)/256, B_IMG);
  k_score<<<gs, 256, 0, stream>>>(preds, sbits, clsA, hist);
  k_thresh<<<B_IMG, 64, 0, stream>>>(hist, thr);
  dim3 g3((NCAND+255)/256, B_IMG);
  k_gather<<<g3, 256, 0, stream>>>(sbits, thr, cnt, cand);
  k_nms<<<B_IMG, 512, 0, stream>>>(preds, clsA, cand, cnt, selb, selc);
  k_proj<<<dim3(192, B_IMG), 256, 0, stream>>>(f1, f2, f3, f4, W1, G);
  k_roi_mlp<<<dim3((MAXDET+3)/4, B_IMG), 256, 0, stream>>>(G, selb, selc, b1, W2, b2, out);
}